// Round 7
// baseline (551.635 us; speedup 1.0000x reference)
//
#include <hip/hip_runtime.h>
#include <hip/hip_bf16.h>

#define N_NODES 50000
#define N_EDGES 800000
#define N_FEAT 128
#define HIDDEN 256
#define N_GRAPHS 256
#define N_CLASSES 10
#define SCAN_NB ((N_NODES + 255) / 256)   // 196 scan blocks

typedef __hip_bfloat16 bf16_t;
typedef short bf16x8 __attribute__((ext_vector_type(8)));
typedef float f32x4 __attribute__((ext_vector_type(4)));

__device__ inline float bfb2f(short s) {
    unsigned u = ((unsigned)(unsigned short)s) << 16;
    float f; __builtin_memcpy(&f, &u, 4); return f;
}
__device__ inline short f2bfb(float f) {
    bf16_t b = __float2bfloat16(f);
    short s; __builtin_memcpy(&s, &b, 2); return s;
}

// ---------------- CSR build ----------------

__global__ void count_deg_kernel(const int* __restrict__ ei, unsigned* __restrict__ deg) {
    int e = blockIdx.x * blockDim.x + threadIdx.x;
    if (e < N_EDGES) atomicAdd(&deg[ei[N_EDGES + e]], 1u);
}

__global__ __launch_bounds__(256) void scan_a_kernel(const unsigned* __restrict__ deg,
                                                     unsigned* __restrict__ rowptr,
                                                     unsigned* __restrict__ blocksum) {
    __shared__ unsigned tmp[256];
    int t = threadIdx.x;
    int g = blockIdx.x * 256 + t;
    unsigned v = (g < N_NODES) ? deg[g] : 0u;
    tmp[t] = v;
    __syncthreads();
    #pragma unroll
    for (int off = 1; off < 256; off <<= 1) {
        unsigned add = (t >= off) ? tmp[t - off] : 0u;
        __syncthreads();
        tmp[t] += add;
        __syncthreads();
    }
    if (g < N_NODES) rowptr[g] = tmp[t] - v;           // exclusive (pre-offset)
    if (t == 255) blocksum[blockIdx.x] = tmp[t];
}

__global__ __launch_bounds__(256) void scan_b_kernel(unsigned* __restrict__ blocksum) {
    __shared__ unsigned tmp[256];
    int t = threadIdx.x;
    unsigned v = (t < SCAN_NB) ? blocksum[t] : 0u;
    tmp[t] = v;
    __syncthreads();
    #pragma unroll
    for (int off = 1; off < 256; off <<= 1) {
        unsigned add = (t >= off) ? tmp[t - off] : 0u;
        __syncthreads();
        tmp[t] += add;
        __syncthreads();
    }
    if (t < SCAN_NB) blocksum[t] = tmp[t] - v;         // exclusive block offsets
}

__global__ __launch_bounds__(256) void scan_c_kernel(unsigned* __restrict__ rowptr,
                                                     const unsigned* __restrict__ blocksum,
                                                     unsigned* __restrict__ cursor) {
    int g = blockIdx.x * 256 + threadIdx.x;
    if (g < N_NODES) {
        unsigned r = rowptr[g] + blocksum[blockIdx.x];
        rowptr[g] = r;
        cursor[g] = r;
    }
    if (g == 0) rowptr[N_NODES] = N_EDGES;
}

__global__ void fill_adj_kernel(const int* __restrict__ ei, unsigned* __restrict__ cursor,
                                int* __restrict__ adj) {
    int e = blockIdx.x * blockDim.x + threadIdx.x;
    if (e < N_EDGES) {
        int src = ei[e];
        int dst = ei[N_EDGES + e];
        unsigned pos = atomicAdd(&cursor[dst], 1u);
        adj[pos] = src;
    }
}

// ---------------- x fp32 -> bf16 convert ----------------

__global__ __launch_bounds__(256) void convert_x_kernel(const float* __restrict__ x,
                                                        bf16_t* __restrict__ xb) {
    int i = blockIdx.x * 256 + threadIdx.x;
    if (i < N_NODES * N_FEAT / 4) {
        float4 v = reinterpret_cast<const float4*>(x)[i];
        short4 o;
        o.x = f2bfb(v.x); o.y = f2bfb(v.y); o.z = f2bfb(v.z); o.w = f2bfb(v.w);
        reinterpret_cast<short4*>(xb)[i] = o;
    }
}

// ---------------- Weight prep: fp32 W[K][256] -> bf16 Wt[256][K] ----------------

__global__ __launch_bounds__(256) void prep_weights_kernel(
    const float* __restrict__ c1_w0, const float* __restrict__ c1_w1,
    const float* __restrict__ cs_w0, const float* __restrict__ cs_w1,
    bf16_t* __restrict__ wt)
{
    __shared__ float T[32][33];
    int z = blockIdx.z;
    const float* src; int K; size_t off;
    if (z == 0)      { src = c1_w0; K = N_FEAT;  off = 0; }
    else if (z == 1) { src = c1_w1; K = HIDDEN;  off = 32768; }
    else {
        int i = (z - 2) >> 1;
        src = (((z - 2) & 1) ? cs_w1 : cs_w0) + (size_t)i * HIDDEN * HIDDEN;
        K = HIDDEN;
        off = 32768 + (size_t)(z - 1) * 65536;
    }
    int k0 = blockIdx.x * 32, n0 = blockIdx.y * 32;
    if (k0 >= K) return;
    int t = threadIdx.x;
    int r = t >> 3, c4 = (t & 7) * 4;
    float4 v = *reinterpret_cast<const float4*>(src + (size_t)(k0 + r) * HIDDEN + n0 + c4);
    T[r][c4 + 0] = v.x; T[r][c4 + 1] = v.y; T[r][c4 + 2] = v.z; T[r][c4 + 3] = v.w;
    __syncthreads();
    int n = t >> 3, kc = (t & 7) * 4;
    short4 o;
    o.x = f2bfb(T[kc + 0][n]); o.y = f2bfb(T[kc + 1][n]);
    o.z = f2bfb(T[kc + 2][n]); o.w = f2bfb(T[kc + 3][n]);
    *reinterpret_cast<short4*>((short*)wt + off + (size_t)(n0 + n) * K + k0 + kc) = o;
}

// ---------------- Aggregation, feature-split passes ----------------
// Cache-blocking: each pass gathers only half the columns -> working set halves
// -> higher per-XCD L2 hit rate on the random gather.

// F=128 (layer 1): 64 cols/pass. 8 lanes x 16B per edge, 8 edges per step, 2x unroll.
__global__ __launch_bounds__(256) void aggregate1_half_kernel(
    const bf16_t* __restrict__ xb, const int* __restrict__ adj,
    const unsigned* __restrict__ rowptr, const float* __restrict__ eps_arr,
    int colOff, bf16_t* __restrict__ out)
{
    int w = threadIdx.x >> 6, lane = threadIdx.x & 63;
    int n = blockIdx.x * 4 + w;
    if (n >= N_NODES) return;
    int g = lane >> 3, l3 = lane & 7;
    unsigned beg = rowptr[n], end = rowptr[n + 1];
    const short* xs = (const short*)xb + colOff;
    float acc[8] = {};
    unsigned e = beg;
    for (; e + 16 <= end; e += 16) {
        int s0 = adj[e + g];
        int s1 = adj[e + 8 + g];
        bf16x8 v0 = *reinterpret_cast<const bf16x8*>(xs + (unsigned)s0 * N_FEAT + l3 * 8);
        bf16x8 v1 = *reinterpret_cast<const bf16x8*>(xs + (unsigned)s1 * N_FEAT + l3 * 8);
        #pragma unroll
        for (int j = 0; j < 8; j++) acc[j] += bfb2f(v0[j]) + bfb2f(v1[j]);
    }
    for (; e + 8 <= end; e += 8) {
        int s0 = adj[e + g];
        bf16x8 v0 = *reinterpret_cast<const bf16x8*>(xs + (unsigned)s0 * N_FEAT + l3 * 8);
        #pragma unroll
        for (int j = 0; j < 8; j++) acc[j] += bfb2f(v0[j]);
    }
    int rem = (int)(end - e);
    if (g < rem) {
        bf16x8 v0 = *reinterpret_cast<const bf16x8*>(xs + (unsigned)adj[e + g] * N_FEAT + l3 * 8);
        #pragma unroll
        for (int j = 0; j < 8; j++) acc[j] += bfb2f(v0[j]);
    }
    if (g == 0) {
        bf16x8 sv = *reinterpret_cast<const bf16x8*>(xs + (unsigned)n * N_FEAT + l3 * 8);
        float ep = 1.f + eps_arr[0];
        #pragma unroll
        for (int j = 0; j < 8; j++) acc[j] += ep * bfb2f(sv[j]);
    }
    #pragma unroll
    for (int j = 0; j < 8; j++) {
        acc[j] += __shfl_xor(acc[j], 8);
        acc[j] += __shfl_xor(acc[j], 16);
        acc[j] += __shfl_xor(acc[j], 32);
    }
    if (lane < 8) {
        bf16x8 o;
        #pragma unroll
        for (int j = 0; j < 8; j++) o[j] = f2bfb(acc[j]);
        *reinterpret_cast<bf16x8*>((short*)out + (unsigned)n * N_FEAT + colOff + l3 * 8) = o;
    }
}

// F=256 (layers 2-4): 128 cols/pass. 16 lanes x 16B per edge, 4 edges per step, 2x unroll.
__global__ __launch_bounds__(256) void aggregate2_half_kernel(
    const bf16_t* __restrict__ x, const int* __restrict__ adj,
    const unsigned* __restrict__ rowptr, const float* __restrict__ eps_arr, int eps_idx,
    int colOff, bf16_t* __restrict__ out)
{
    int w = threadIdx.x >> 6, lane = threadIdx.x & 63;
    int n = blockIdx.x * 4 + w;
    if (n >= N_NODES) return;
    int g = lane >> 4, l4 = lane & 15;
    unsigned beg = rowptr[n], end = rowptr[n + 1];
    const short* xs = (const short*)x + colOff;
    float acc[8] = {};
    unsigned e = beg;
    for (; e + 8 <= end; e += 8) {
        int s0 = adj[e + g];
        int s1 = adj[e + 4 + g];
        bf16x8 v0 = *reinterpret_cast<const bf16x8*>(xs + (unsigned)s0 * HIDDEN + l4 * 8);
        bf16x8 v1 = *reinterpret_cast<const bf16x8*>(xs + (unsigned)s1 * HIDDEN + l4 * 8);
        #pragma unroll
        for (int j = 0; j < 8; j++) acc[j] += bfb2f(v0[j]) + bfb2f(v1[j]);
    }
    for (; e + 4 <= end; e += 4) {
        int s0 = adj[e + g];
        bf16x8 v0 = *reinterpret_cast<const bf16x8*>(xs + (unsigned)s0 * HIDDEN + l4 * 8);
        #pragma unroll
        for (int j = 0; j < 8; j++) acc[j] += bfb2f(v0[j]);
    }
    int rem = (int)(end - e);
    if (g < rem) {
        bf16x8 v0 = *reinterpret_cast<const bf16x8*>(xs + (unsigned)adj[e + g] * HIDDEN + l4 * 8);
        #pragma unroll
        for (int j = 0; j < 8; j++) acc[j] += bfb2f(v0[j]);
    }
    if (g == 0) {
        bf16x8 sv = *reinterpret_cast<const bf16x8*>(xs + (unsigned)n * HIDDEN + l4 * 8);
        float ep = 1.f + eps_arr[eps_idx];
        #pragma unroll
        for (int j = 0; j < 8; j++) acc[j] += ep * bfb2f(sv[j]);
    }
    #pragma unroll
    for (int j = 0; j < 8; j++) {
        acc[j] += __shfl_xor(acc[j], 16);
        acc[j] += __shfl_xor(acc[j], 32);
    }
    if (lane < 16) {
        bf16x8 o;
        #pragma unroll
        for (int j = 0; j < 8; j++) o[j] = f2bfb(acc[j]);
        *reinterpret_cast<bf16x8*>((short*)out + (unsigned)n * HIDDEN + colOff + l4 * 8) = o;
    }
}

// ---------------- bf16 MFMA GEMM: C[M][256] = act(A[M][K] @ W) ----------------
// 128x128 tile, 512 threads (8 waves, 2x4), BK=64. Wave tile 64x32, 4x2 mfma frags.

#define GBM 128
#define GBN 128
#define GBK 64

__global__ __launch_bounds__(512) void gemm_bf16_kernel(
    const bf16_t* __restrict__ A, const bf16_t* __restrict__ Wt,
    const float* __restrict__ bias, bf16_t* __restrict__ C,
    int M, int K,
    const float* __restrict__ bn_g, const float* __restrict__ bn_b,
    const float* __restrict__ bn_m, const float* __restrict__ bn_v, int do_bn)
{
    __shared__ short lds[18432];                       // 36.9 KB
    short (*As)[72] = reinterpret_cast<short(*)[72]>(lds);          // [128][72]
    short (*Bs)[72] = reinterpret_cast<short(*)[72]>(lds + 9216);   // [128][72]
    short (*Cs)[136] = reinterpret_cast<short(*)[136]>(lds);        // [128][136] (overlay)

    int tid = threadIdx.x;
    int lane = tid & 63;
    int wave = tid >> 6;
    int wr = wave >> 2, wc = wave & 3;                 // 2 x 4 wave grid
    int row0 = blockIdx.x * GBM, col0 = blockIdx.y * GBN;

    int lrow = tid >> 3, lch = tid & 7;                // 64 rows x 8 chunks per pass, 2 passes

    const short* Ab = (const short*)A;
    const short* Wb = (const short*)Wt;

    f32x4 acc[4][2] = {};

    for (int k0 = 0; k0 < K; k0 += GBK) {
        #pragma unroll
        for (int rr = 0; rr < 2; rr++) {
            int r = lrow + rr * 64;
            int arow = row0 + r;
            bf16x8 av = {};
            if (arow < M)
                av = *reinterpret_cast<const bf16x8*>(Ab + (size_t)arow * K + k0 + lch * 8);
            *reinterpret_cast<bf16x8*>(&As[r][lch * 8]) = av;
            bf16x8 bv = *reinterpret_cast<const bf16x8*>(Wb + (size_t)(col0 + r) * K + k0 + lch * 8);
            *reinterpret_cast<bf16x8*>(&Bs[r][lch * 8]) = bv;
        }
        __syncthreads();

        int fr = lane & 15, fk = (lane >> 4) * 8;
        #pragma unroll
        for (int ks = 0; ks < 2; ks++) {
            bf16x8 a[4], b[2];
            #pragma unroll
            for (int m = 0; m < 4; m++)
                a[m] = *reinterpret_cast<const bf16x8*>(&As[wr * 64 + m * 16 + fr][ks * 32 + fk]);
            #pragma unroll
            for (int n = 0; n < 2; n++)
                b[n] = *reinterpret_cast<const bf16x8*>(&Bs[wc * 32 + n * 16 + fr][ks * 32 + fk]);
            #pragma unroll
            for (int m = 0; m < 4; m++)
                #pragma unroll
                for (int n = 0; n < 2; n++)
                    acc[m][n] = __builtin_amdgcn_mfma_f32_16x16x32_bf16(a[m], b[n], acc[m][n], 0, 0, 0);
        }
        __syncthreads();
    }

    #pragma unroll
    for (int m = 0; m < 4; m++) {
        #pragma unroll
        for (int n = 0; n < 2; n++) {
            int rl = wr * 64 + m * 16 + (lane >> 4) * 4;
            int cl = wc * 32 + n * 16 + (lane & 15);
            int c = col0 + cl;
            float bi = bias[c];
            #pragma unroll
            for (int r = 0; r < 4; r++) {
                float v = acc[m][n][r] + bi;
                v = fmaxf(v, 0.f);
                if (do_bn) v = (v - bn_m[c]) * rsqrtf(bn_v[c] + 1e-5f) * bn_g[c] + bn_b[c];
                Cs[rl + r][cl] = f2bfb(v);
            }
        }
    }
    __syncthreads();
    int lr = tid >> 2, c16 = tid & 3;
    int r = row0 + lr;
    if (r < M) {
        short* Cb = (short*)C;
        #pragma unroll
        for (int cc = 0; cc < 4; cc++) {
            int ch = c16 + cc * 4;
            bf16x8 cv = *reinterpret_cast<const bf16x8*>(&Cs[lr][ch * 8]);
            *reinterpret_cast<bf16x8*>(Cb + (size_t)r * HIDDEN + col0 + ch * 8) = cv;
        }
    }
}

// ---------------- Pool ----------------

__global__ __launch_bounds__(256) void pool_kernel(const bf16_t* __restrict__ h,
                                                   const int* __restrict__ batch,
                                                   float* __restrict__ pooled) {
    __shared__ int sbs[2];
    __shared__ float red[4][HIDDEN];
    int g = blockIdx.x;
    if (threadIdx.x == 0) {
        int lo = 0, hi = N_NODES;
        while (lo < hi) { int mid = (lo + hi) >> 1; if (batch[mid] < g) lo = mid + 1; else hi = mid; }
        sbs[0] = lo;
        hi = N_NODES;
        while (lo < hi) { int mid = (lo + hi) >> 1; if (batch[mid] < g + 1) lo = mid + 1; else hi = mid; }
        sbs[1] = lo;
    }
    __syncthreads();
    int sbeg = sbs[0], send = sbs[1];
    int w = threadIdx.x >> 6, lane = threadIdx.x & 63;
    int half = lane >> 5, l5 = lane & 31;
    const short* hb = (const short*)h;
    float acc[8] = {};
    for (int n = sbeg + w * 2 + half; n < send; n += 8) {
        bf16x8 v = *reinterpret_cast<const bf16x8*>(hb + (size_t)n * HIDDEN + l5 * 8);
        #pragma unroll
        for (int j = 0; j < 8; j++) acc[j] += bfb2f(v[j]);
    }
    #pragma unroll
    for (int j = 0; j < 8; j++) acc[j] += __shfl_xor(acc[j], 32);
    if (half == 0) {
        #pragma unroll
        for (int j = 0; j < 8; j++) red[w][l5 * 8 + j] = acc[j];
    }
    __syncthreads();
    int t = threadIdx.x;
    float s = red[0][t] + red[1][t] + red[2][t] + red[3][t];
    float cnt = (float)(send - sbeg);
    pooled[g * HIDDEN + t] = s / fmaxf(cnt, 1.f);
}

// ---------------- Head ----------------

__global__ void head_kernel(const float* __restrict__ pooled,
                            const float* __restrict__ w1, const float* __restrict__ b1,
                            const float* __restrict__ w2, const float* __restrict__ b2,
                            float* __restrict__ out) {
    int g = blockIdx.x, t = threadIdx.x;
    __shared__ float p[HIDDEN];
    __shared__ float h1[HIDDEN];
    __shared__ float lg[N_CLASSES];
    p[t] = pooled[g * HIDDEN + t];
    __syncthreads();
    float acc = b1[t];
    for (int k = 0; k < HIDDEN; k++) acc += p[k] * w1[k * HIDDEN + t];
    h1[t] = fmaxf(acc, 0.f);
    __syncthreads();
    if (t < N_CLASSES) {
        float a = b2[t];
        for (int k = 0; k < HIDDEN; k++) a += h1[k] * w2[k * N_CLASSES + t];
        lg[t] = a;
    }
    __syncthreads();
    if (t == 0) {
        float mx = lg[0];
        for (int j = 1; j < N_CLASSES; j++) mx = fmaxf(mx, lg[j]);
        float se = 0.f;
        for (int j = 0; j < N_CLASSES; j++) se += expf(lg[j] - mx);
        float lse = mx + logf(se);
        for (int j = 0; j < N_CLASSES; j++) out[g * N_CLASSES + j] = lg[j] - lse;
    }
}

// ---------------- Launch ----------------

extern "C" void kernel_launch(void* const* d_in, const int* in_sizes, int n_in,
                              void* d_out, int out_size, void* d_ws, size_t ws_size,
                              hipStream_t stream) {
    const float* x       = (const float*)d_in[0];
    const int*   ei      = (const int*)d_in[1];     // int32 on device (harness contract)
    const int*   batch   = (const int*)d_in[2];
    const float* c1_w0   = (const float*)d_in[3];
    const float* c1_b0   = (const float*)d_in[4];
    const float* c1_w1   = (const float*)d_in[5];
    const float* c1_b1   = (const float*)d_in[6];
    const float* c1_g    = (const float*)d_in[7];
    const float* c1_be   = (const float*)d_in[8];
    const float* c1_m    = (const float*)d_in[9];
    const float* c1_v    = (const float*)d_in[10];
    const float* cs_w0   = (const float*)d_in[11];
    const float* cs_b0   = (const float*)d_in[12];
    const float* cs_w1   = (const float*)d_in[13];
    const float* cs_b1   = (const float*)d_in[14];
    const float* cs_g    = (const float*)d_in[15];
    const float* cs_be   = (const float*)d_in[16];
    const float* cs_m    = (const float*)d_in[17];
    const float* cs_v    = (const float*)d_in[18];
    const float* eps     = (const float*)d_in[19];
    const float* lin1_w  = (const float*)d_in[20];
    const float* lin1_b  = (const float*)d_in[21];
    const float* lin2_w  = (const float*)d_in[22];
    const float* lin2_b  = (const float*)d_in[23];

    char* ws = (char*)d_ws;
    size_t off = 0;
    auto alloc = [&](size_t bytes) -> void* {
        void* p = ws + off;
        off += (bytes + 255) & ~(size_t)255;
        return p;
    };

    unsigned* deg      = (unsigned*)alloc(N_NODES * 4);
    unsigned* rowptr   = (unsigned*)alloc((N_NODES + 1) * 4);
    unsigned* cursor   = (unsigned*)alloc(N_NODES * 4);
    unsigned* blocksum = (unsigned*)alloc(SCAN_NB * 4);
    int*      adj      = (int*)alloc(N_EDGES * 4);
    bf16_t*   Wt       = (bf16_t*)alloc((size_t)(32768 + 7 * 65536) * 2);
    bf16_t*   xb       = (bf16_t*)alloc((size_t)N_NODES * N_FEAT * 2);
    bf16_t*   B1       = (bf16_t*)alloc((size_t)N_NODES * HIDDEN * 2);
    bf16_t*   B2       = (bf16_t*)alloc((size_t)N_NODES * HIDDEN * 2);
    bf16_t*   B3       = (bf16_t*)alloc((size_t)N_NODES * HIDDEN * 2);
    float*    pooled   = (float*)alloc(N_GRAPHS * HIDDEN * 4);

    bf16_t* wt_10 = Wt;                       // c1_w0^T  [256][128]
    bf16_t* wt_11 = Wt + 32768;               // c1_w1^T  [256][256]
    auto wt_c0 = [&](int i) { return Wt + 32768 + (size_t)(1 + 2 * i) * 65536; };
    auto wt_c1 = [&](int i) { return Wt + 32768 + (size_t)(2 + 2 * i) * 65536; };

    hipMemsetAsync(deg, 0, N_NODES * 4, stream);

    int eb = (N_EDGES + 255) / 256;
    count_deg_kernel<<<eb, 256, 0, stream>>>(ei, deg);
    scan_a_kernel<<<SCAN_NB, 256, 0, stream>>>(deg, rowptr, blocksum);
    scan_b_kernel<<<1, 256, 0, stream>>>(blocksum);
    scan_c_kernel<<<SCAN_NB, 256, 0, stream>>>(rowptr, blocksum, cursor);
    fill_adj_kernel<<<eb, 256, 0, stream>>>(ei, cursor, adj);

    convert_x_kernel<<<(N_NODES * N_FEAT / 4 + 255) / 256, 256, 0, stream>>>(x, xb);
    prep_weights_kernel<<<dim3(8, 8, 8), 256, 0, stream>>>(c1_w0, c1_w1, cs_w0, cs_w1, Wt);

    dim3 ggrid((N_NODES + GBM - 1) / GBM, HIDDEN / GBN);
    int ab = (N_NODES + 3) / 4;

    // Layer 1 (F=128): two feature-half passes (working set 6.4 MB each)
    aggregate1_half_kernel<<<ab, 256, 0, stream>>>(xb, adj, rowptr, eps, 0, B1);
    aggregate1_half_kernel<<<ab, 256, 0, stream>>>(xb, adj, rowptr, eps, 64, B1);
    gemm_bf16_kernel<<<ggrid, 512, 0, stream>>>(B1, wt_10, c1_b0, B2, N_NODES, N_FEAT,
                                                nullptr, nullptr, nullptr, nullptr, 0);
    gemm_bf16_kernel<<<ggrid, 512, 0, stream>>>(B2, wt_11, c1_b1, B3, N_NODES, HIDDEN,
                                                c1_g, c1_be, c1_m, c1_v, 1);

    // Layers 2..4 (F=256): two feature-half passes (working set 12.8 MB each)
    for (int i = 0; i < 3; i++) {
        aggregate2_half_kernel<<<ab, 256, 0, stream>>>(B3, adj, rowptr, eps, i + 1, 0, B1);
        aggregate2_half_kernel<<<ab, 256, 0, stream>>>(B3, adj, rowptr, eps, i + 1, 128, B1);
        gemm_bf16_kernel<<<ggrid, 512, 0, stream>>>(B1, wt_c0(i), cs_b0 + i * HIDDEN, B2,
                                                    N_NODES, HIDDEN,
                                                    nullptr, nullptr, nullptr, nullptr, 0);
        gemm_bf16_kernel<<<ggrid, 512, 0, stream>>>(B2, wt_c1(i), cs_b1 + i * HIDDEN, B3,
                                                    N_NODES, HIDDEN,
                                                    cs_g + i * HIDDEN, cs_be + i * HIDDEN,
                                                    cs_m + i * HIDDEN, cs_v + i * HIDDEN, 1);
    }

    pool_kernel<<<N_GRAPHS, 256, 0, stream>>>(B3, batch, pooled);
    head_kernel<<<N_GRAPHS, HIDDEN, 0, stream>>>(pooled, lin1_w, lin1_b, lin2_w, lin2_b, (float*)d_out);
}

// Round 8
// 514.626 us; speedup vs baseline: 1.0719x; 1.0719x over previous
//
#include <hip/hip_runtime.h>
#include <hip/hip_bf16.h>

#define N_NODES 50000
#define N_EDGES 800000
#define N_FEAT 128
#define HIDDEN 256
#define N_GRAPHS 256
#define N_CLASSES 10

#define NBUCK ((N_NODES + 255) / 256)      // 196 dst-buckets of 256 nodes
#define EPB 2048                           // edges per scatter block
#define NBLK_S ((N_EDGES + EPB - 1) / EPB) // 391

typedef __hip_bfloat16 bf16_t;
typedef short bf16x8 __attribute__((ext_vector_type(8)));
typedef float f32x4 __attribute__((ext_vector_type(4)));

__device__ inline float bfb2f(short s) {
    unsigned u = ((unsigned)(unsigned short)s) << 16;
    float f; __builtin_memcpy(&f, &u, 4); return f;
}
__device__ inline short f2bfb(float f) {
    bf16_t b = __float2bfloat16(f);
    short s; __builtin_memcpy(&s, &b, 2); return s;
}

// ---------------- CSR build: two-level bucket sort, no fine random scatter ----------------

// S1: per-(block,bucket) histogram
__global__ __launch_bounds__(256) void bucket_hist_kernel(const int* __restrict__ ei,
                                                          unsigned* __restrict__ histG) {
    __shared__ unsigned lh[NBUCK];
    int t = threadIdx.x, j = blockIdx.x;
    for (int i = t; i < NBUCK; i += 256) lh[i] = 0;
    __syncthreads();
    int base = j * EPB;
    #pragma unroll
    for (int it = 0; it < EPB / 256; it++) {
        int e = base + it * 256 + t;
        if (e < N_EDGES) atomicAdd(&lh[(unsigned)ei[N_EDGES + e] >> 8], 1u);
    }
    __syncthreads();
    for (int i = t; i < NBUCK; i += 256) histG[(size_t)j * NBUCK + i] = lh[i];
}

// S2: column scan over blocks per bucket, then bucket-base scan; hist becomes absolute offsets
__global__ __launch_bounds__(256) void bucket_scan_kernel(unsigned* __restrict__ histG,
                                                          unsigned* __restrict__ bucketBase) {
    __shared__ unsigned tmp[256];
    int t = threadIdx.x;
    unsigned run = 0;
    if (t < NBUCK) {
        for (int j = 0; j < NBLK_S; j++) {
            unsigned v = histG[(size_t)j * NBUCK + t];
            histG[(size_t)j * NBUCK + t] = run;
            run += v;
        }
    }
    unsigned v = (t < NBUCK) ? run : 0;
    tmp[t] = v;
    __syncthreads();
    for (int off = 1; off < 256; off <<= 1) {
        unsigned a = (t >= off) ? tmp[t - off] : 0u;
        __syncthreads();
        tmp[t] += a;
        __syncthreads();
    }
    unsigned base = tmp[t] - v;
    if (t < NBUCK) {
        bucketBase[t] = base;
        for (int j = 0; j < NBLK_S; j++) histG[(size_t)j * NBUCK + t] += base;
    }
    if (t == NBUCK - 1) bucketBase[NBUCK] = base + v;
}

// S3: scatter (src,dst) pairs into per-(block,bucket) contiguous runs
__global__ __launch_bounds__(256) void bucket_scatter_kernel(const int* __restrict__ ei,
                                                             const unsigned* __restrict__ histG,
                                                             unsigned long long* __restrict__ ebuf) {
    __shared__ unsigned lcur[NBUCK];
    int t = threadIdx.x, j = blockIdx.x;
    for (int i = t; i < NBUCK; i += 256) lcur[i] = histG[(size_t)j * NBUCK + i];
    __syncthreads();
    int base = j * EPB;
    #pragma unroll
    for (int it = 0; it < EPB / 256; it++) {
        int e = base + it * 256 + t;
        if (e < N_EDGES) {
            unsigned src = (unsigned)ei[e];
            unsigned dst = (unsigned)ei[N_EDGES + e];
            unsigned pos = atomicAdd(&lcur[dst >> 8], 1u);
            ebuf[pos] = (unsigned long long)src | ((unsigned long long)dst << 32);
        }
    }
}

// F: one block per bucket: local degree count + scan -> rowptr; place adj in private window
__global__ __launch_bounds__(256) void fine_fill_kernel(const unsigned long long* __restrict__ ebuf,
                                                        const unsigned* __restrict__ bucketBase,
                                                        unsigned* __restrict__ rowptr,
                                                        int* __restrict__ adj) {
    __shared__ unsigned ldeg[256], lcur[256], tmp[256];
    int b = blockIdx.x, t = threadIdx.x;
    unsigned sbase = bucketBase[b];
    int scnt = (int)(bucketBase[b + 1] - sbase);
    ldeg[t] = 0;
    __syncthreads();
    for (int k = t; k < scnt; k += 256) {
        unsigned dst = (unsigned)(ebuf[sbase + k] >> 32);
        atomicAdd(&ldeg[dst & 255], 1u);
    }
    __syncthreads();
    unsigned v = ldeg[t];
    tmp[t] = v;
    __syncthreads();
    for (int off = 1; off < 256; off <<= 1) {
        unsigned a = (t >= off) ? tmp[t - off] : 0u;
        __syncthreads();
        tmp[t] += a;
        __syncthreads();
    }
    unsigned exc = tmp[t] - v;
    lcur[t] = exc;
    int gnode = b * 256 + t;
    if (gnode < N_NODES) rowptr[gnode] = sbase + exc;
    if (b == NBUCK - 1 && t == 0) rowptr[N_NODES] = N_EDGES;
    __syncthreads();
    for (int k = t; k < scnt; k += 256) {
        unsigned long long p = ebuf[sbase + k];
        unsigned dst = (unsigned)(p >> 32);
        unsigned pos = atomicAdd(&lcur[dst & 255], 1u);
        adj[sbase + pos] = (int)(p & 0xffffffffu);
    }
}

// ---------------- x fp32 -> bf16 convert ----------------

__global__ __launch_bounds__(256) void convert_x_kernel(const float* __restrict__ x,
                                                        bf16_t* __restrict__ xb) {
    int i = blockIdx.x * 256 + threadIdx.x;
    if (i < N_NODES * N_FEAT / 4) {
        float4 v = reinterpret_cast<const float4*>(x)[i];
        short4 o;
        o.x = f2bfb(v.x); o.y = f2bfb(v.y); o.z = f2bfb(v.z); o.w = f2bfb(v.w);
        reinterpret_cast<short4*>(xb)[i] = o;
    }
}

// ---------------- Weight prep: fp32 W[K][256] -> bf16 Wt[256][K] ----------------

__global__ __launch_bounds__(256) void prep_weights_kernel(
    const float* __restrict__ c1_w0, const float* __restrict__ c1_w1,
    const float* __restrict__ cs_w0, const float* __restrict__ cs_w1,
    bf16_t* __restrict__ wt)
{
    __shared__ float T[32][33];
    int z = blockIdx.z;
    const float* src; int K; size_t off;
    if (z == 0)      { src = c1_w0; K = N_FEAT;  off = 0; }
    else if (z == 1) { src = c1_w1; K = HIDDEN;  off = 32768; }
    else {
        int i = (z - 2) >> 1;
        src = (((z - 2) & 1) ? cs_w1 : cs_w0) + (size_t)i * HIDDEN * HIDDEN;
        K = HIDDEN;
        off = 32768 + (size_t)(z - 1) * 65536;
    }
    int k0 = blockIdx.x * 32, n0 = blockIdx.y * 32;
    if (k0 >= K) return;
    int t = threadIdx.x;
    int r = t >> 3, c4 = (t & 7) * 4;
    float4 v = *reinterpret_cast<const float4*>(src + (size_t)(k0 + r) * HIDDEN + n0 + c4);
    T[r][c4 + 0] = v.x; T[r][c4 + 1] = v.y; T[r][c4 + 2] = v.z; T[r][c4 + 3] = v.w;
    __syncthreads();
    int n = t >> 3, kc = (t & 7) * 4;
    short4 o;
    o.x = f2bfb(T[kc + 0][n]); o.y = f2bfb(T[kc + 1][n]);
    o.z = f2bfb(T[kc + 2][n]); o.w = f2bfb(T[kc + 3][n]);
    *reinterpret_cast<short4*>((short*)wt + off + (size_t)(n0 + n) * K + k0 + kc) = o;
}

// ---------------- Aggregation layer 1: bf16 xb[N][128] -> bf16 out[N][128] ----------------
// One wave per node; quarter-wave (16 lanes x 16B) per edge, 8 edges in flight.

__global__ __launch_bounds__(256) void aggregate1_kernel(
    const bf16_t* __restrict__ xb, const int* __restrict__ adj,
    const unsigned* __restrict__ rowptr, const float* __restrict__ eps_arr,
    bf16_t* __restrict__ out)
{
    int w = threadIdx.x >> 6, lane = threadIdx.x & 63;
    int n = blockIdx.x * 4 + w;
    if (n >= N_NODES) return;
    int q = lane >> 4, l4 = lane & 15;
    unsigned beg = rowptr[n], end = rowptr[n + 1];
    const short* xs = (const short*)xb;
    float acc[8] = {};
    unsigned e = beg;
    for (; e + 8 <= end; e += 8) {
        int s0 = adj[e + q];
        int s1 = adj[e + 4 + q];
        bf16x8 v0 = *reinterpret_cast<const bf16x8*>(xs + (unsigned)s0 * N_FEAT + l4 * 8);
        bf16x8 v1 = *reinterpret_cast<const bf16x8*>(xs + (unsigned)s1 * N_FEAT + l4 * 8);
        #pragma unroll
        for (int j = 0; j < 8; j++) acc[j] += bfb2f(v0[j]) + bfb2f(v1[j]);
    }
    for (; e + 4 <= end; e += 4) {
        int s0 = adj[e + q];
        bf16x8 v0 = *reinterpret_cast<const bf16x8*>(xs + (unsigned)s0 * N_FEAT + l4 * 8);
        #pragma unroll
        for (int j = 0; j < 8; j++) acc[j] += bfb2f(v0[j]);
    }
    int rem = (int)(end - e);
    if (q < rem) {
        bf16x8 v0 = *reinterpret_cast<const bf16x8*>(xs + (unsigned)adj[e + q] * N_FEAT + l4 * 8);
        #pragma unroll
        for (int j = 0; j < 8; j++) acc[j] += bfb2f(v0[j]);
    }
    if (q == 0) {
        bf16x8 sv = *reinterpret_cast<const bf16x8*>(xs + (unsigned)n * N_FEAT + l4 * 8);
        float ep = 1.f + eps_arr[0];
        #pragma unroll
        for (int j = 0; j < 8; j++) acc[j] += ep * bfb2f(sv[j]);
    }
    #pragma unroll
    for (int j = 0; j < 8; j++) {
        acc[j] += __shfl_xor(acc[j], 16);
        acc[j] += __shfl_xor(acc[j], 32);
    }
    if (lane < 16) {
        bf16x8 o;
        #pragma unroll
        for (int j = 0; j < 8; j++) o[j] = f2bfb(acc[j]);
        *reinterpret_cast<bf16x8*>((short*)out + (unsigned)n * N_FEAT + l4 * 8) = o;
    }
}

// ---------------- Aggregation layers 2-4: bf16 [N][256] -> bf16 [N][256] ----------------
// Half-wave (32 lanes x 16B) per edge, 8 edges in flight.

__global__ __launch_bounds__(256) void aggregate2_kernel(
    const bf16_t* __restrict__ x, const int* __restrict__ adj,
    const unsigned* __restrict__ rowptr, const float* __restrict__ eps_arr, int eps_idx,
    bf16_t* __restrict__ out)
{
    int w = threadIdx.x >> 6, lane = threadIdx.x & 63;
    int n = blockIdx.x * 4 + w;
    if (n >= N_NODES) return;
    int half = lane >> 5, l5 = lane & 31;
    unsigned beg = rowptr[n], end = rowptr[n + 1];
    const short* xs = (const short*)x;
    float acc[8] = {};
    unsigned e = beg;
    for (; e + 8 <= end; e += 8) {
        int s0 = adj[e + half];
        int s1 = adj[e + 2 + half];
        int s2 = adj[e + 4 + half];
        int s3 = adj[e + 6 + half];
        bf16x8 v0 = *reinterpret_cast<const bf16x8*>(xs + (unsigned)s0 * HIDDEN + l5 * 8);
        bf16x8 v1 = *reinterpret_cast<const bf16x8*>(xs + (unsigned)s1 * HIDDEN + l5 * 8);
        bf16x8 v2 = *reinterpret_cast<const bf16x8*>(xs + (unsigned)s2 * HIDDEN + l5 * 8);
        bf16x8 v3 = *reinterpret_cast<const bf16x8*>(xs + (unsigned)s3 * HIDDEN + l5 * 8);
        #pragma unroll
        for (int j = 0; j < 8; j++)
            acc[j] += (bfb2f(v0[j]) + bfb2f(v1[j])) + (bfb2f(v2[j]) + bfb2f(v3[j]));
    }
    for (; e + 2 <= end; e += 2) {
        int s0 = adj[e + half];
        bf16x8 v0 = *reinterpret_cast<const bf16x8*>(xs + (unsigned)s0 * HIDDEN + l5 * 8);
        #pragma unroll
        for (int j = 0; j < 8; j++) acc[j] += bfb2f(v0[j]);
    }
    if (e < end && half == 0) {
        bf16x8 v0 = *reinterpret_cast<const bf16x8*>(xs + (unsigned)adj[e] * HIDDEN + l5 * 8);
        #pragma unroll
        for (int j = 0; j < 8; j++) acc[j] += bfb2f(v0[j]);
    }
    if (half == 0) {
        bf16x8 sv = *reinterpret_cast<const bf16x8*>(xs + (unsigned)n * HIDDEN + l5 * 8);
        float ep = 1.f + eps_arr[eps_idx];
        #pragma unroll
        for (int j = 0; j < 8; j++) acc[j] += ep * bfb2f(sv[j]);
    }
    #pragma unroll
    for (int j = 0; j < 8; j++) acc[j] += __shfl_xor(acc[j], 32);
    if (half == 0) {
        bf16x8 o;
        #pragma unroll
        for (int j = 0; j < 8; j++) o[j] = f2bfb(acc[j]);
        *reinterpret_cast<bf16x8*>((short*)out + (unsigned)n * HIDDEN + l5 * 8) = o;
    }
}

// ---------------- bf16 MFMA GEMM: C[M][256] = act(A[M][K] @ W) ----------------
// 128x128 tile, 512 threads (8 waves, 2x4), BK=64. Wave tile 64x32, 4x2 mfma frags.

#define GBM 128
#define GBN 128
#define GBK 64

__global__ __launch_bounds__(512) void gemm_bf16_kernel(
    const bf16_t* __restrict__ A, const bf16_t* __restrict__ Wt,
    const float* __restrict__ bias, bf16_t* __restrict__ C,
    int M, int K,
    const float* __restrict__ bn_g, const float* __restrict__ bn_b,
    const float* __restrict__ bn_m, const float* __restrict__ bn_v, int do_bn)
{
    __shared__ short lds[18432];                       // 36.9 KB
    short (*As)[72] = reinterpret_cast<short(*)[72]>(lds);          // [128][72]
    short (*Bs)[72] = reinterpret_cast<short(*)[72]>(lds + 9216);   // [128][72]
    short (*Cs)[136] = reinterpret_cast<short(*)[136]>(lds);        // [128][136] (overlay)

    int tid = threadIdx.x;
    int lane = tid & 63;
    int wave = tid >> 6;
    int wr = wave >> 2, wc = wave & 3;                 // 2 x 4 wave grid
    int row0 = blockIdx.x * GBM, col0 = blockIdx.y * GBN;

    int lrow = tid >> 3, lch = tid & 7;                // 64 rows x 8 chunks per pass, 2 passes

    const short* Ab = (const short*)A;
    const short* Wb = (const short*)Wt;

    f32x4 acc[4][2] = {};

    for (int k0 = 0; k0 < K; k0 += GBK) {
        #pragma unroll
        for (int rr = 0; rr < 2; rr++) {
            int r = lrow + rr * 64;
            int arow = row0 + r;
            bf16x8 av = {};
            if (arow < M)
                av = *reinterpret_cast<const bf16x8*>(Ab + (size_t)arow * K + k0 + lch * 8);
            *reinterpret_cast<bf16x8*>(&As[r][lch * 8]) = av;
            bf16x8 bv = *reinterpret_cast<const bf16x8*>(Wb + (size_t)(col0 + r) * K + k0 + lch * 8);
            *reinterpret_cast<bf16x8*>(&Bs[r][lch * 8]) = bv;
        }
        __syncthreads();

        int fr = lane & 15, fk = (lane >> 4) * 8;
        #pragma unroll
        for (int ks = 0; ks < 2; ks++) {
            bf16x8 a[4], b[2];
            #pragma unroll
            for (int m = 0; m < 4; m++)
                a[m] = *reinterpret_cast<const bf16x8*>(&As[wr * 64 + m * 16 + fr][ks * 32 + fk]);
            #pragma unroll
            for (int n = 0; n < 2; n++)
                b[n] = *reinterpret_cast<const bf16x8*>(&Bs[wc * 32 + n * 16 + fr][ks * 32 + fk]);
            #pragma unroll
            for (int m = 0; m < 4; m++)
                #pragma unroll
                for (int n = 0; n < 2; n++)
                    acc[m][n] = __builtin_amdgcn_mfma_f32_16x16x32_bf16(a[m], b[n], acc[m][n], 0, 0, 0);
        }
        __syncthreads();
    }

    #pragma unroll
    for (int m = 0; m < 4; m++) {
        #pragma unroll
        for (int n = 0; n < 2; n++) {
            int rl = wr * 64 + m * 16 + (lane >> 4) * 4;
            int cl = wc * 32 + n * 16 + (lane & 15);
            int c = col0 + cl;
            float bi = bias[c];
            #pragma unroll
            for (int r = 0; r < 4; r++) {
                float v = acc[m][n][r] + bi;
                v = fmaxf(v, 0.f);
                if (do_bn) v = (v - bn_m[c]) * rsqrtf(bn_v[c] + 1e-5f) * bn_g[c] + bn_b[c];
                Cs[rl + r][cl] = f2bfb(v);
            }
        }
    }
    __syncthreads();
    int lr = tid >> 2, c16 = tid & 3;
    int r = row0 + lr;
    if (r < M) {
        short* Cb = (short*)C;
        #pragma unroll
        for (int cc = 0; cc < 4; cc++) {
            int ch = c16 + cc * 4;
            bf16x8 cv = *reinterpret_cast<const bf16x8*>(&Cs[lr][ch * 8]);
            *reinterpret_cast<bf16x8*>(Cb + (size_t)r * HIDDEN + col0 + ch * 8) = cv;
        }
    }
}

// ---------------- Pool ----------------

__global__ __launch_bounds__(256) void pool_kernel(const bf16_t* __restrict__ h,
                                                   const int* __restrict__ batch,
                                                   float* __restrict__ pooled) {
    __shared__ int sbs[2];
    __shared__ float red[4][HIDDEN];
    int g = blockIdx.x;
    if (threadIdx.x == 0) {
        int lo = 0, hi = N_NODES;
        while (lo < hi) { int mid = (lo + hi) >> 1; if (batch[mid] < g) lo = mid + 1; else hi = mid; }
        sbs[0] = lo;
        hi = N_NODES;
        while (lo < hi) { int mid = (lo + hi) >> 1; if (batch[mid] < g + 1) lo = mid + 1; else hi = mid; }
        sbs[1] = lo;
    }
    __syncthreads();
    int sbeg = sbs[0], send = sbs[1];
    int w = threadIdx.x >> 6, lane = threadIdx.x & 63;
    int half = lane >> 5, l5 = lane & 31;
    const short* hb = (const short*)h;
    float acc[8] = {};
    for (int n = sbeg + w * 2 + half; n < send; n += 8) {
        bf16x8 v = *reinterpret_cast<const bf16x8*>(hb + (size_t)n * HIDDEN + l5 * 8);
        #pragma unroll
        for (int j = 0; j < 8; j++) acc[j] += bfb2f(v[j]);
    }
    #pragma unroll
    for (int j = 0; j < 8; j++) acc[j] += __shfl_xor(acc[j], 32);
    if (half == 0) {
        #pragma unroll
        for (int j = 0; j < 8; j++) red[w][l5 * 8 + j] = acc[j];
    }
    __syncthreads();
    int t = threadIdx.x;
    float s = red[0][t] + red[1][t] + red[2][t] + red[3][t];
    float cnt = (float)(send - sbeg);
    pooled[g * HIDDEN + t] = s / fmaxf(cnt, 1.f);
}

// ---------------- Head ----------------

__global__ void head_kernel(const float* __restrict__ pooled,
                            const float* __restrict__ w1, const float* __restrict__ b1,
                            const float* __restrict__ w2, const float* __restrict__ b2,
                            float* __restrict__ out) {
    int g = blockIdx.x, t = threadIdx.x;
    __shared__ float p[HIDDEN];
    __shared__ float h1[HIDDEN];
    __shared__ float lg[N_CLASSES];
    p[t] = pooled[g * HIDDEN + t];
    __syncthreads();
    float acc = b1[t];
    for (int k = 0; k < HIDDEN; k++) acc += p[k] * w1[k * HIDDEN + t];
    h1[t] = fmaxf(acc, 0.f);
    __syncthreads();
    if (t < N_CLASSES) {
        float a = b2[t];
        for (int k = 0; k < HIDDEN; k++) a += h1[k] * w2[k * N_CLASSES + t];
        lg[t] = a;
    }
    __syncthreads();
    if (t == 0) {
        float mx = lg[0];
        for (int j = 1; j < N_CLASSES; j++) mx = fmaxf(mx, lg[j]);
        float se = 0.f;
        for (int j = 0; j < N_CLASSES; j++) se += expf(lg[j] - mx);
        float lse = mx + logf(se);
        for (int j = 0; j < N_CLASSES; j++) out[g * N_CLASSES + j] = lg[j] - lse;
    }
}

// ---------------- Launch ----------------

extern "C" void kernel_launch(void* const* d_in, const int* in_sizes, int n_in,
                              void* d_out, int out_size, void* d_ws, size_t ws_size,
                              hipStream_t stream) {
    const float* x       = (const float*)d_in[0];
    const int*   ei      = (const int*)d_in[1];     // int32 on device (harness contract)
    const int*   batch   = (const int*)d_in[2];
    const float* c1_w0   = (const float*)d_in[3];
    const float* c1_b0   = (const float*)d_in[4];
    const float* c1_w1   = (const float*)d_in[5];
    const float* c1_b1   = (const float*)d_in[6];
    const float* c1_g    = (const float*)d_in[7];
    const float* c1_be   = (const float*)d_in[8];
    const float* c1_m    = (const float*)d_in[9];
    const float* c1_v    = (const float*)d_in[10];
    const float* cs_w0   = (const float*)d_in[11];
    const float* cs_b0   = (const float*)d_in[12];
    const float* cs_w1   = (const float*)d_in[13];
    const float* cs_b1   = (const float*)d_in[14];
    const float* cs_g    = (const float*)d_in[15];
    const float* cs_be   = (const float*)d_in[16];
    const float* cs_m    = (const float*)d_in[17];
    const float* cs_v    = (const float*)d_in[18];
    const float* eps     = (const float*)d_in[19];
    const float* lin1_w  = (const float*)d_in[20];
    const float* lin1_b  = (const float*)d_in[21];
    const float* lin2_w  = (const float*)d_in[22];
    const float* lin2_b  = (const float*)d_in[23];

    char* ws = (char*)d_ws;
    size_t off = 0;
    auto alloc = [&](size_t bytes) -> void* {
        void* p = ws + off;
        off += (bytes + 255) & ~(size_t)255;
        return p;
    };

    unsigned* histG      = (unsigned*)alloc((size_t)NBLK_S * NBUCK * 4);
    unsigned* bucketBase = (unsigned*)alloc((NBUCK + 1) * 4);
    unsigned long long* ebuf = (unsigned long long*)alloc((size_t)N_EDGES * 8);
    unsigned* rowptr     = (unsigned*)alloc((N_NODES + 1) * 4);
    int*      adj        = (int*)alloc(N_EDGES * 4);
    bf16_t*   Wt         = (bf16_t*)alloc((size_t)(32768 + 7 * 65536) * 2);
    bf16_t*   xb         = (bf16_t*)alloc((size_t)N_NODES * N_FEAT * 2);
    bf16_t*   B1         = (bf16_t*)alloc((size_t)N_NODES * HIDDEN * 2);
    bf16_t*   B2         = (bf16_t*)alloc((size_t)N_NODES * HIDDEN * 2);
    bf16_t*   B3         = (bf16_t*)alloc((size_t)N_NODES * HIDDEN * 2);
    float*    pooled     = (float*)alloc(N_GRAPHS * HIDDEN * 4);

    bf16_t* wt_10 = Wt;                       // c1_w0^T  [256][128]
    bf16_t* wt_11 = Wt + 32768;               // c1_w1^T  [256][256]
    auto wt_c0 = [&](int i) { return Wt + 32768 + (size_t)(1 + 2 * i) * 65536; };
    auto wt_c1 = [&](int i) { return Wt + 32768 + (size_t)(2 + 2 * i) * 65536; };

    // CSR build (4 dispatches, no memset, no fine random scatter)
    bucket_hist_kernel<<<NBLK_S, 256, 0, stream>>>(ei, histG);
    bucket_scan_kernel<<<1, 256, 0, stream>>>(histG, bucketBase);
    bucket_scatter_kernel<<<NBLK_S, 256, 0, stream>>>(ei, histG, ebuf);
    fine_fill_kernel<<<NBUCK, 256, 0, stream>>>(ebuf, bucketBase, rowptr, adj);

    convert_x_kernel<<<(N_NODES * N_FEAT / 4 + 255) / 256, 256, 0, stream>>>(x, xb);
    prep_weights_kernel<<<dim3(8, 8, 8), 256, 0, stream>>>(c1_w0, c1_w1, cs_w0, cs_w1, Wt);

    dim3 ggrid((N_NODES + GBM - 1) / GBM, HIDDEN / GBN);
    int ab = (N_NODES + 3) / 4;

    // Layer 1 (F=128)
    aggregate1_kernel<<<ab, 256, 0, stream>>>(xb, adj, rowptr, eps, B1);
    gemm_bf16_kernel<<<ggrid, 512, 0, stream>>>(B1, wt_10, c1_b0, B2, N_NODES, N_FEAT,
                                                nullptr, nullptr, nullptr, nullptr, 0);
    gemm_bf16_kernel<<<ggrid, 512, 0, stream>>>(B2, wt_11, c1_b1, B3, N_NODES, HIDDEN,
                                                c1_g, c1_be, c1_m, c1_v, 1);

    // Layers 2..4 (F=256)
    for (int i = 0; i < 3; i++) {
        aggregate2_kernel<<<ab, 256, 0, stream>>>(B3, adj, rowptr, eps, i + 1, B1);
        gemm_bf16_kernel<<<ggrid, 512, 0, stream>>>(B1, wt_c0(i), cs_b0 + i * HIDDEN, B2,
                                                    N_NODES, HIDDEN,
                                                    nullptr, nullptr, nullptr, nullptr, 0);
        gemm_bf16_kernel<<<ggrid, 512, 0, stream>>>(B2, wt_c1(i), cs_b1 + i * HIDDEN, B3,
                                                    N_NODES, HIDDEN,
                                                    cs_g + i * HIDDEN, cs_be + i * HIDDEN,
                                                    cs_m + i * HIDDEN, cs_v + i * HIDDEN, 1);
    }

    pool_kernel<<<N_GRAPHS, 256, 0, stream>>>(B3, batch, pooled);
    head_kernel<<<N_GRAPHS, HIDDEN, 0, stream>>>(pooled, lin1_w, lin1_b, lin2_w, lin2_b, (float*)d_out);
}

// Round 9
// 460.947 us; speedup vs baseline: 1.1967x; 1.1165x over previous
//
#include <hip/hip_runtime.h>
#include <hip/hip_bf16.h>

#define N_NODES 50000
#define N_EDGES 800000
#define N_FEAT 128
#define HIDDEN 256
#define N_GRAPHS 256
#define N_CLASSES 10

#define NBUCK ((N_NODES + 255) / 256)      // 196 dst-buckets of 256 nodes
#define EPB 2048                           // edges per scatter block
#define NBLK_S ((N_EDGES + EPB - 1) / EPB) // 391

typedef __hip_bfloat16 bf16_t;
typedef short bf16x8 __attribute__((ext_vector_type(8)));
typedef float f32x4 __attribute__((ext_vector_type(4)));

__device__ inline float bfb2f(short s) {
    unsigned u = ((unsigned)(unsigned short)s) << 16;
    float f; __builtin_memcpy(&f, &u, 4); return f;
}
__device__ inline short f2bfb(float f) {
    bf16_t b = __float2bfloat16(f);
    short s; __builtin_memcpy(&s, &b, 2); return s;
}

// ---------------- CSR build: two-level bucket sort, parallel scans ----------------

// S1: per-(block,bucket) histogram, stored TRANSPOSED: histT[bucket][block]
__global__ __launch_bounds__(256) void bucket_hist_kernel(const int* __restrict__ ei,
                                                          unsigned* __restrict__ histT) {
    __shared__ unsigned lh[NBUCK];
    int t = threadIdx.x, j = blockIdx.x;
    for (int i = t; i < NBUCK; i += 256) lh[i] = 0;
    __syncthreads();
    int base = j * EPB;
    #pragma unroll
    for (int it = 0; it < EPB / 256; it++) {
        int e = base + it * 256 + t;
        if (e < N_EDGES) atomicAdd(&lh[(unsigned)ei[N_EDGES + e] >> 8], 1u);
    }
    __syncthreads();
    for (int i = t; i < NBUCK; i += 256) histT[(size_t)i * NBLK_S + j] = lh[i];
}

// S2a: one block per bucket — contiguous 391-element exclusive scan in-place + bucket total
__global__ __launch_bounds__(256) void bucket_scan_a_kernel(unsigned* __restrict__ histT,
                                                            unsigned* __restrict__ bucketTot) {
    __shared__ unsigned tmp[256];
    int b = blockIdx.x, t = threadIdx.x;
    unsigned* row = histT + (size_t)b * NBLK_S;
    int i0 = t * 2, i1 = t * 2 + 1;
    unsigned v0 = (i0 < NBLK_S) ? row[i0] : 0u;
    unsigned v1 = (i1 < NBLK_S) ? row[i1] : 0u;
    unsigned s = v0 + v1;
    tmp[t] = s;
    __syncthreads();
    #pragma unroll
    for (int off = 1; off < 256; off <<= 1) {
        unsigned a = (t >= off) ? tmp[t - off] : 0u;
        __syncthreads();
        tmp[t] += a;
        __syncthreads();
    }
    unsigned base = tmp[t] - s;          // exclusive chunk base
    if (i0 < NBLK_S) row[i0] = base;
    if (i1 < NBLK_S) row[i1] = base + v0;
    if (t == 255) bucketTot[b] = tmp[255];
}

// S2b: scan the 196 bucket totals -> bucket bases
__global__ __launch_bounds__(256) void bucket_scan_b_kernel(const unsigned* __restrict__ bucketTot,
                                                            unsigned* __restrict__ bucketBase) {
    __shared__ unsigned tmp[256];
    int t = threadIdx.x;
    unsigned v = (t < NBUCK) ? bucketTot[t] : 0u;
    tmp[t] = v;
    __syncthreads();
    #pragma unroll
    for (int off = 1; off < 256; off <<= 1) {
        unsigned a = (t >= off) ? tmp[t - off] : 0u;
        __syncthreads();
        tmp[t] += a;
        __syncthreads();
    }
    if (t < NBUCK) bucketBase[t] = tmp[t] - v;
    if (t == NBUCK - 1) bucketBase[NBUCK] = tmp[t];
}

// S3: scatter (src,dst) pairs into per-(block,bucket) contiguous runs
__global__ __launch_bounds__(256) void bucket_scatter_kernel(const int* __restrict__ ei,
                                                             const unsigned* __restrict__ histT,
                                                             const unsigned* __restrict__ bucketBase,
                                                             unsigned long long* __restrict__ ebuf) {
    __shared__ unsigned lcur[NBUCK];
    int t = threadIdx.x, j = blockIdx.x;
    for (int i = t; i < NBUCK; i += 256)
        lcur[i] = histT[(size_t)i * NBLK_S + j] + bucketBase[i];
    __syncthreads();
    int base = j * EPB;
    #pragma unroll
    for (int it = 0; it < EPB / 256; it++) {
        int e = base + it * 256 + t;
        if (e < N_EDGES) {
            unsigned src = (unsigned)ei[e];
            unsigned dst = (unsigned)ei[N_EDGES + e];
            unsigned pos = atomicAdd(&lcur[dst >> 8], 1u);
            ebuf[pos] = (unsigned long long)src | ((unsigned long long)dst << 32);
        }
    }
}

// F: one block per bucket: local degree count + scan -> rowptr; place adj in private window
__global__ __launch_bounds__(256) void fine_fill_kernel(const unsigned long long* __restrict__ ebuf,
                                                        const unsigned* __restrict__ bucketBase,
                                                        unsigned* __restrict__ rowptr,
                                                        int* __restrict__ adj) {
    __shared__ unsigned ldeg[256], lcur[256], tmp[256];
    int b = blockIdx.x, t = threadIdx.x;
    unsigned sbase = bucketBase[b];
    int scnt = (int)(bucketBase[b + 1] - sbase);
    ldeg[t] = 0;
    __syncthreads();
    for (int k = t; k < scnt; k += 256) {
        unsigned dst = (unsigned)(ebuf[sbase + k] >> 32);
        atomicAdd(&ldeg[dst & 255], 1u);
    }
    __syncthreads();
    unsigned v = ldeg[t];
    tmp[t] = v;
    __syncthreads();
    for (int off = 1; off < 256; off <<= 1) {
        unsigned a = (t >= off) ? tmp[t - off] : 0u;
        __syncthreads();
        tmp[t] += a;
        __syncthreads();
    }
    unsigned exc = tmp[t] - v;
    lcur[t] = exc;
    int gnode = b * 256 + t;
    if (gnode < N_NODES) rowptr[gnode] = sbase + exc;
    if (b == NBUCK - 1 && t == 0) rowptr[N_NODES] = N_EDGES;
    __syncthreads();
    for (int k = t; k < scnt; k += 256) {
        unsigned long long p = ebuf[sbase + k];
        unsigned dst = (unsigned)(p >> 32);
        unsigned pos = atomicAdd(&lcur[dst & 255], 1u);
        adj[sbase + pos] = (int)(p & 0xffffffffu);
    }
}

// ---------------- x fp32 -> bf16 convert ----------------

__global__ __launch_bounds__(256) void convert_x_kernel(const float* __restrict__ x,
                                                        bf16_t* __restrict__ xb) {
    int i = blockIdx.x * 256 + threadIdx.x;
    if (i < N_NODES * N_FEAT / 4) {
        float4 v = reinterpret_cast<const float4*>(x)[i];
        short4 o;
        o.x = f2bfb(v.x); o.y = f2bfb(v.y); o.z = f2bfb(v.z); o.w = f2bfb(v.w);
        reinterpret_cast<short4*>(xb)[i] = o;
    }
}

// ---------------- Weight prep: fp32 W[K][256] -> bf16 Wt[256][K] ----------------

__global__ __launch_bounds__(256) void prep_weights_kernel(
    const float* __restrict__ c1_w0, const float* __restrict__ c1_w1,
    const float* __restrict__ cs_w0, const float* __restrict__ cs_w1,
    bf16_t* __restrict__ wt)
{
    __shared__ float T[32][33];
    int z = blockIdx.z;
    const float* src; int K; size_t off;
    if (z == 0)      { src = c1_w0; K = N_FEAT;  off = 0; }
    else if (z == 1) { src = c1_w1; K = HIDDEN;  off = 32768; }
    else {
        int i = (z - 2) >> 1;
        src = (((z - 2) & 1) ? cs_w1 : cs_w0) + (size_t)i * HIDDEN * HIDDEN;
        K = HIDDEN;
        off = 32768 + (size_t)(z - 1) * 65536;
    }
    int k0 = blockIdx.x * 32, n0 = blockIdx.y * 32;
    if (k0 >= K) return;
    int t = threadIdx.x;
    int r = t >> 3, c4 = (t & 7) * 4;
    float4 v = *reinterpret_cast<const float4*>(src + (size_t)(k0 + r) * HIDDEN + n0 + c4);
    T[r][c4 + 0] = v.x; T[r][c4 + 1] = v.y; T[r][c4 + 2] = v.z; T[r][c4 + 3] = v.w;
    __syncthreads();
    int n = t >> 3, kc = (t & 7) * 4;
    short4 o;
    o.x = f2bfb(T[kc + 0][n]); o.y = f2bfb(T[kc + 1][n]);
    o.z = f2bfb(T[kc + 2][n]); o.w = f2bfb(T[kc + 3][n]);
    *reinterpret_cast<short4*>((short*)wt + off + (size_t)(n0 + n) * K + k0 + kc) = o;
}

// ---------------- Aggregation layer 1: bf16 xb[N][128] -> bf16 out[N][128] ----------------
// One wave per node; quarter-wave (16 lanes x 16B) per edge, 8 edges in flight.

__global__ __launch_bounds__(256) void aggregate1_kernel(
    const bf16_t* __restrict__ xb, const int* __restrict__ adj,
    const unsigned* __restrict__ rowptr, const float* __restrict__ eps_arr,
    bf16_t* __restrict__ out)
{
    int w = threadIdx.x >> 6, lane = threadIdx.x & 63;
    int n = blockIdx.x * 4 + w;
    if (n >= N_NODES) return;
    int q = lane >> 4, l4 = lane & 15;
    unsigned beg = rowptr[n], end = rowptr[n + 1];
    const short* xs = (const short*)xb;
    float acc[8] = {};
    unsigned e = beg;
    for (; e + 8 <= end; e += 8) {
        int s0 = adj[e + q];
        int s1 = adj[e + 4 + q];
        bf16x8 v0 = *reinterpret_cast<const bf16x8*>(xs + (unsigned)s0 * N_FEAT + l4 * 8);
        bf16x8 v1 = *reinterpret_cast<const bf16x8*>(xs + (unsigned)s1 * N_FEAT + l4 * 8);
        #pragma unroll
        for (int j = 0; j < 8; j++) acc[j] += bfb2f(v0[j]) + bfb2f(v1[j]);
    }
    for (; e + 4 <= end; e += 4) {
        int s0 = adj[e + q];
        bf16x8 v0 = *reinterpret_cast<const bf16x8*>(xs + (unsigned)s0 * N_FEAT + l4 * 8);
        #pragma unroll
        for (int j = 0; j < 8; j++) acc[j] += bfb2f(v0[j]);
    }
    int rem = (int)(end - e);
    if (q < rem) {
        bf16x8 v0 = *reinterpret_cast<const bf16x8*>(xs + (unsigned)adj[e + q] * N_FEAT + l4 * 8);
        #pragma unroll
        for (int j = 0; j < 8; j++) acc[j] += bfb2f(v0[j]);
    }
    if (q == 0) {
        bf16x8 sv = *reinterpret_cast<const bf16x8*>(xs + (unsigned)n * N_FEAT + l4 * 8);
        float ep = 1.f + eps_arr[0];
        #pragma unroll
        for (int j = 0; j < 8; j++) acc[j] += ep * bfb2f(sv[j]);
    }
    #pragma unroll
    for (int j = 0; j < 8; j++) {
        acc[j] += __shfl_xor(acc[j], 16);
        acc[j] += __shfl_xor(acc[j], 32);
    }
    if (lane < 16) {
        bf16x8 o;
        #pragma unroll
        for (int j = 0; j < 8; j++) o[j] = f2bfb(acc[j]);
        *reinterpret_cast<bf16x8*>((short*)out + (unsigned)n * N_FEAT + l4 * 8) = o;
    }
}

// ---------------- Aggregation layers 2-4: bf16 [N][256] -> bf16 [N][256] ----------------
// Half-wave (32 lanes x 16B) per edge, 8 edges in flight.

__global__ __launch_bounds__(256) void aggregate2_kernel(
    const bf16_t* __restrict__ x, const int* __restrict__ adj,
    const unsigned* __restrict__ rowptr, const float* __restrict__ eps_arr, int eps_idx,
    bf16_t* __restrict__ out)
{
    int w = threadIdx.x >> 6, lane = threadIdx.x & 63;
    int n = blockIdx.x * 4 + w;
    if (n >= N_NODES) return;
    int half = lane >> 5, l5 = lane & 31;
    unsigned beg = rowptr[n], end = rowptr[n + 1];
    const short* xs = (const short*)x;
    float acc[8] = {};
    unsigned e = beg;
    for (; e + 8 <= end; e += 8) {
        int s0 = adj[e + half];
        int s1 = adj[e + 2 + half];
        int s2 = adj[e + 4 + half];
        int s3 = adj[e + 6 + half];
        bf16x8 v0 = *reinterpret_cast<const bf16x8*>(xs + (unsigned)s0 * HIDDEN + l5 * 8);
        bf16x8 v1 = *reinterpret_cast<const bf16x8*>(xs + (unsigned)s1 * HIDDEN + l5 * 8);
        bf16x8 v2 = *reinterpret_cast<const bf16x8*>(xs + (unsigned)s2 * HIDDEN + l5 * 8);
        bf16x8 v3 = *reinterpret_cast<const bf16x8*>(xs + (unsigned)s3 * HIDDEN + l5 * 8);
        #pragma unroll
        for (int j = 0; j < 8; j++)
            acc[j] += (bfb2f(v0[j]) + bfb2f(v1[j])) + (bfb2f(v2[j]) + bfb2f(v3[j]));
    }
    for (; e + 2 <= end; e += 2) {
        int s0 = adj[e + half];
        bf16x8 v0 = *reinterpret_cast<const bf16x8*>(xs + (unsigned)s0 * HIDDEN + l5 * 8);
        #pragma unroll
        for (int j = 0; j < 8; j++) acc[j] += bfb2f(v0[j]);
    }
    if (e < end && half == 0) {
        bf16x8 v0 = *reinterpret_cast<const bf16x8*>(xs + (unsigned)adj[e] * HIDDEN + l5 * 8);
        #pragma unroll
        for (int j = 0; j < 8; j++) acc[j] += bfb2f(v0[j]);
    }
    if (half == 0) {
        bf16x8 sv = *reinterpret_cast<const bf16x8*>(xs + (unsigned)n * HIDDEN + l5 * 8);
        float ep = 1.f + eps_arr[eps_idx];
        #pragma unroll
        for (int j = 0; j < 8; j++) acc[j] += ep * bfb2f(sv[j]);
    }
    #pragma unroll
    for (int j = 0; j < 8; j++) acc[j] += __shfl_xor(acc[j], 32);
    if (half == 0) {
        bf16x8 o;
        #pragma unroll
        for (int j = 0; j < 8; j++) o[j] = f2bfb(acc[j]);
        *reinterpret_cast<bf16x8*>((short*)out + (unsigned)n * HIDDEN + l5 * 8) = o;
    }
}

// ---------------- bf16 MFMA GEMM: C[M][256] = act(A[M][K] @ W) ----------------
// 128x128 tile, 512 threads (8 waves, 2x4), BK=64. Wave tile 64x32, 4x2 mfma frags.

#define GBM 128
#define GBN 128
#define GBK 64

__global__ __launch_bounds__(512) void gemm_bf16_kernel(
    const bf16_t* __restrict__ A, const bf16_t* __restrict__ Wt,
    const float* __restrict__ bias, bf16_t* __restrict__ C,
    int M, int K,
    const float* __restrict__ bn_g, const float* __restrict__ bn_b,
    const float* __restrict__ bn_m, const float* __restrict__ bn_v, int do_bn)
{
    __shared__ short lds[18432];                       // 36.9 KB
    short (*As)[72] = reinterpret_cast<short(*)[72]>(lds);          // [128][72]
    short (*Bs)[72] = reinterpret_cast<short(*)[72]>(lds + 9216);   // [128][72]
    short (*Cs)[136] = reinterpret_cast<short(*)[136]>(lds);        // [128][136] (overlay)

    int tid = threadIdx.x;
    int lane = tid & 63;
    int wave = tid >> 6;
    int wr = wave >> 2, wc = wave & 3;                 // 2 x 4 wave grid
    int row0 = blockIdx.x * GBM, col0 = blockIdx.y * GBN;

    int lrow = tid >> 3, lch = tid & 7;                // 64 rows x 8 chunks per pass, 2 passes

    const short* Ab = (const short*)A;
    const short* Wb = (const short*)Wt;

    f32x4 acc[4][2] = {};

    for (int k0 = 0; k0 < K; k0 += GBK) {
        #pragma unroll
        for (int rr = 0; rr < 2; rr++) {
            int r = lrow + rr * 64;
            int arow = row0 + r;
            bf16x8 av = {};
            if (arow < M)
                av = *reinterpret_cast<const bf16x8*>(Ab + (size_t)arow * K + k0 + lch * 8);
            *reinterpret_cast<bf16x8*>(&As[r][lch * 8]) = av;
            bf16x8 bv = *reinterpret_cast<const bf16x8*>(Wb + (size_t)(col0 + r) * K + k0 + lch * 8);
            *reinterpret_cast<bf16x8*>(&Bs[r][lch * 8]) = bv;
        }
        __syncthreads();

        int fr = lane & 15, fk = (lane >> 4) * 8;
        #pragma unroll
        for (int ks = 0; ks < 2; ks++) {
            bf16x8 a[4], b[2];
            #pragma unroll
            for (int m = 0; m < 4; m++)
                a[m] = *reinterpret_cast<const bf16x8*>(&As[wr * 64 + m * 16 + fr][ks * 32 + fk]);
            #pragma unroll
            for (int n = 0; n < 2; n++)
                b[n] = *reinterpret_cast<const bf16x8*>(&Bs[wc * 32 + n * 16 + fr][ks * 32 + fk]);
            #pragma unroll
            for (int m = 0; m < 4; m++)
                #pragma unroll
                for (int n = 0; n < 2; n++)
                    acc[m][n] = __builtin_amdgcn_mfma_f32_16x16x32_bf16(a[m], b[n], acc[m][n], 0, 0, 0);
        }
        __syncthreads();
    }

    #pragma unroll
    for (int m = 0; m < 4; m++) {
        #pragma unroll
        for (int n = 0; n < 2; n++) {
            int rl = wr * 64 + m * 16 + (lane >> 4) * 4;
            int cl = wc * 32 + n * 16 + (lane & 15);
            int c = col0 + cl;
            float bi = bias[c];
            #pragma unroll
            for (int r = 0; r < 4; r++) {
                float v = acc[m][n][r] + bi;
                v = fmaxf(v, 0.f);
                if (do_bn) v = (v - bn_m[c]) * rsqrtf(bn_v[c] + 1e-5f) * bn_g[c] + bn_b[c];
                Cs[rl + r][cl] = f2bfb(v);
            }
        }
    }
    __syncthreads();
    int lr = tid >> 2, c16 = tid & 3;
    int r = row0 + lr;
    if (r < M) {
        short* Cb = (short*)C;
        #pragma unroll
        for (int cc = 0; cc < 4; cc++) {
            int ch = c16 + cc * 4;
            bf16x8 cv = *reinterpret_cast<const bf16x8*>(&Cs[lr][ch * 8]);
            *reinterpret_cast<bf16x8*>(Cb + (size_t)r * HIDDEN + col0 + ch * 8) = cv;
        }
    }
}

// ---------------- Pool ----------------

__global__ __launch_bounds__(256) void pool_kernel(const bf16_t* __restrict__ h,
                                                   const int* __restrict__ batch,
                                                   float* __restrict__ pooled) {
    __shared__ int sbs[2];
    __shared__ float red[4][HIDDEN];
    int g = blockIdx.x;
    if (threadIdx.x == 0) {
        int lo = 0, hi = N_NODES;
        while (lo < hi) { int mid = (lo + hi) >> 1; if (batch[mid] < g) lo = mid + 1; else hi = mid; }
        sbs[0] = lo;
        hi = N_NODES;
        while (lo < hi) { int mid = (lo + hi) >> 1; if (batch[mid] < g + 1) lo = mid + 1; else hi = mid; }
        sbs[1] = lo;
    }
    __syncthreads();
    int sbeg = sbs[0], send = sbs[1];
    int w = threadIdx.x >> 6, lane = threadIdx.x & 63;
    int half = lane >> 5, l5 = lane & 31;
    const short* hb = (const short*)h;
    float acc[8] = {};
    for (int n = sbeg + w * 2 + half; n < send; n += 8) {
        bf16x8 v = *reinterpret_cast<const bf16x8*>(hb + (size_t)n * HIDDEN + l5 * 8);
        #pragma unroll
        for (int j = 0; j < 8; j++) acc[j] += bfb2f(v[j]);
    }
    #pragma unroll
    for (int j = 0; j < 8; j++) acc[j] += __shfl_xor(acc[j], 32);
    if (half == 0) {
        #pragma unroll
        for (int j = 0; j < 8; j++) red[w][l5 * 8 + j] = acc[j];
    }
    __syncthreads();
    int t = threadIdx.x;
    float s = red[0][t] + red[1][t] + red[2][t] + red[3][t];
    float cnt = (float)(send - sbeg);
    pooled[g * HIDDEN + t] = s / fmaxf(cnt, 1.f);
}

// ---------------- Head ----------------

__global__ void head_kernel(const float* __restrict__ pooled,
                            const float* __restrict__ w1, const float* __restrict__ b1,
                            const float* __restrict__ w2, const float* __restrict__ b2,
                            float* __restrict__ out) {
    int g = blockIdx.x, t = threadIdx.x;
    __shared__ float p[HIDDEN];
    __shared__ float h1[HIDDEN];
    __shared__ float lg[N_CLASSES];
    p[t] = pooled[g * HIDDEN + t];
    __syncthreads();
    float acc = b1[t];
    for (int k = 0; k < HIDDEN; k++) acc += p[k] * w1[k * HIDDEN + t];
    h1[t] = fmaxf(acc, 0.f);
    __syncthreads();
    if (t < N_CLASSES) {
        float a = b2[t];
        for (int k = 0; k < HIDDEN; k++) a += h1[k] * w2[k * N_CLASSES + t];
        lg[t] = a;
    }
    __syncthreads();
    if (t == 0) {
        float mx = lg[0];
        for (int j = 1; j < N_CLASSES; j++) mx = fmaxf(mx, lg[j]);
        float se = 0.f;
        for (int j = 0; j < N_CLASSES; j++) se += expf(lg[j] - mx);
        float lse = mx + logf(se);
        for (int j = 0; j < N_CLASSES; j++) out[g * N_CLASSES + j] = lg[j] - lse;
    }
}

// ---------------- Launch ----------------

extern "C" void kernel_launch(void* const* d_in, const int* in_sizes, int n_in,
                              void* d_out, int out_size, void* d_ws, size_t ws_size,
                              hipStream_t stream) {
    const float* x       = (const float*)d_in[0];
    const int*   ei      = (const int*)d_in[1];     // int32 on device (harness contract)
    const int*   batch   = (const int*)d_in[2];
    const float* c1_w0   = (const float*)d_in[3];
    const float* c1_b0   = (const float*)d_in[4];
    const float* c1_w1   = (const float*)d_in[5];
    const float* c1_b1   = (const float*)d_in[6];
    const float* c1_g    = (const float*)d_in[7];
    const float* c1_be   = (const float*)d_in[8];
    const float* c1_m    = (const float*)d_in[9];
    const float* c1_v    = (const float*)d_in[10];
    const float* cs_w0   = (const float*)d_in[11];
    const float* cs_b0   = (const float*)d_in[12];
    const float* cs_w1   = (const float*)d_in[13];
    const float* cs_b1   = (const float*)d_in[14];
    const float* cs_g    = (const float*)d_in[15];
    const float* cs_be   = (const float*)d_in[16];
    const float* cs_m    = (const float*)d_in[17];
    const float* cs_v    = (const float*)d_in[18];
    const float* eps     = (const float*)d_in[19];
    const float* lin1_w  = (const float*)d_in[20];
    const float* lin1_b  = (const float*)d_in[21];
    const float* lin2_w  = (const float*)d_in[22];
    const float* lin2_b  = (const float*)d_in[23];

    char* ws = (char*)d_ws;
    size_t off = 0;
    auto alloc = [&](size_t bytes) -> void* {
        void* p = ws + off;
        off += (bytes + 255) & ~(size_t)255;
        return p;
    };

    unsigned* histT      = (unsigned*)alloc((size_t)NBUCK * NBLK_S * 4);
    unsigned* bucketTot  = (unsigned*)alloc(NBUCK * 4);
    unsigned* bucketBase = (unsigned*)alloc((NBUCK + 1) * 4);
    unsigned long long* ebuf = (unsigned long long*)alloc((size_t)N_EDGES * 8);
    unsigned* rowptr     = (unsigned*)alloc((N_NODES + 1) * 4);
    int*      adj        = (int*)alloc(N_EDGES * 4);
    bf16_t*   Wt         = (bf16_t*)alloc((size_t)(32768 + 7 * 65536) * 2);
    bf16_t*   xb         = (bf16_t*)alloc((size_t)N_NODES * N_FEAT * 2);
    bf16_t*   B1         = (bf16_t*)alloc((size_t)N_NODES * HIDDEN * 2);
    bf16_t*   B2         = (bf16_t*)alloc((size_t)N_NODES * HIDDEN * 2);
    bf16_t*   B3         = (bf16_t*)alloc((size_t)N_NODES * HIDDEN * 2);
    float*    pooled     = (float*)alloc(N_GRAPHS * HIDDEN * 4);

    bf16_t* wt_10 = Wt;                       // c1_w0^T  [256][128]
    bf16_t* wt_11 = Wt + 32768;               // c1_w1^T  [256][256]
    auto wt_c0 = [&](int i) { return Wt + 32768 + (size_t)(1 + 2 * i) * 65536; };
    auto wt_c1 = [&](int i) { return Wt + 32768 + (size_t)(2 + 2 * i) * 65536; };

    // CSR build (5 dispatches, all parallel)
    bucket_hist_kernel<<<NBLK_S, 256, 0, stream>>>(ei, histT);
    bucket_scan_a_kernel<<<NBUCK, 256, 0, stream>>>(histT, bucketTot);
    bucket_scan_b_kernel<<<1, 256, 0, stream>>>(bucketTot, bucketBase);
    bucket_scatter_kernel<<<NBLK_S, 256, 0, stream>>>(ei, histT, bucketBase, ebuf);
    fine_fill_kernel<<<NBUCK, 256, 0, stream>>>(ebuf, bucketBase, rowptr, adj);

    convert_x_kernel<<<(N_NODES * N_FEAT / 4 + 255) / 256, 256, 0, stream>>>(x, xb);
    prep_weights_kernel<<<dim3(8, 8, 8), 256, 0, stream>>>(c1_w0, c1_w1, cs_w0, cs_w1, Wt);

    dim3 ggrid((N_NODES + GBM - 1) / GBM, HIDDEN / GBN);
    int ab = (N_NODES + 3) / 4;

    // Layer 1 (F=128)
    aggregate1_kernel<<<ab, 256, 0, stream>>>(xb, adj, rowptr, eps, B1);
    gemm_bf16_kernel<<<ggrid, 512, 0, stream>>>(B1, wt_10, c1_b0, B2, N_NODES, N_FEAT,
                                                nullptr, nullptr, nullptr, nullptr, 0);
    gemm_bf16_kernel<<<ggrid, 512, 0, stream>>>(B2, wt_11, c1_b1, B3, N_NODES, HIDDEN,
                                                c1_g, c1_be, c1_m, c1_v, 1);

    // Layers 2..4 (F=256)
    for (int i = 0; i < 3; i++) {
        aggregate2_kernel<<<ab, 256, 0, stream>>>(B3, adj, rowptr, eps, i + 1, B1);
        gemm_bf16_kernel<<<ggrid, 512, 0, stream>>>(B1, wt_c0(i), cs_b0 + i * HIDDEN, B2,
                                                    N_NODES, HIDDEN,
                                                    nullptr, nullptr, nullptr, nullptr, 0);
        gemm_bf16_kernel<<<ggrid, 512, 0, stream>>>(B2, wt_c1(i), cs_b1 + i * HIDDEN, B3,
                                                    N_NODES, HIDDEN,
                                                    cs_g + i * HIDDEN, cs_be + i * HIDDEN,
                                                    cs_m + i * HIDDEN, cs_v + i * HIDDEN, 1);
    }

    pool_kernel<<<N_GRAPHS, 256, 0, stream>>>(B3, batch, pooled);
    head_kernel<<<N_GRAPHS, HIDDEN, 0, stream>>>(pooled, lin1_w, lin1_b, lin2_w, lin2_b, (float*)d_out);
}